// Round 2
// 186.617 us; speedup vs baseline: 1.0012x; 1.0012x over previous
//
#include <hip/hip_runtime.h>
#include <cfloat>

namespace {
constexpr int H = 256;
constexpr int A = 4096;
constexpr int B = 32;
constexpr int G = 512;
constexpr int K = 16;
constexpr size_t SLICE = (size_t)A * H;   // elements per batch slice = 1,048,576
}

static __device__ __forceinline__ float4 f4max(float4 a, float4 b) {
    float4 r;
    r.x = fmaxf(a.x, b.x);
    r.y = fmaxf(a.y, b.y);
    r.z = fmaxf(a.z, b.z);
    r.w = fmaxf(a.w, b.w);
    return r;
}

static __device__ __forceinline__ float4 ntload4(const float* p) {
    // Non-temporal 16B load: x is streamed once with zero reuse; keep it from
    // evicting the rowmax lines (phase-2's working set) out of L2.
    float4 v;
    v.x = __builtin_nontemporal_load(p + 0);
    v.y = __builtin_nontemporal_load(p + 1);
    v.z = __builtin_nontemporal_load(p + 2);
    v.w = __builtin_nontemporal_load(p + 3);
    return v;
}

// Phase 1: rowmax[a*H + h] = max_b x[b*SLICE + a*H + h], but ONLY for rows a
// that actually appear in idx. With 8192 uniform draws from 4096 rows,
// E[distinct] = 4096*(1-e^-2) ~= 3542, so ~13.5% of the 134 MB read is skippable.
//
// 1024 blocks x 256 threads. Block bk owns rows [bk*4, bk*4+4); wave w owns row
// bk*4+w (64 lanes x float4 = 256 floats = one row -> every load is a fully
// coalesced contiguous 1 KiB transaction). Before streaming, the block scans
// idx (32 KB, L2-resident after the first few blocks; ~33 MB aggregate L2
// traffic ~= 1 us, hidden under other blocks' HBM streams) and sets a 4-entry
// LDS usage flag; unused waves exit before touching HBM. This keeps the skip
// launch-neutral: no extra kernel, no extra dependency in the graph.
__global__ __launch_bounds__(256) void rowmax_kernel(const float* __restrict__ x,
                                                     const int* __restrict__ idx,
                                                     float* __restrict__ rowmax) {
    __shared__ int used[4];
    const int tid = threadIdx.x;
    const int bk  = blockIdx.x;               // row group = rows [bk*4, bk*4+4)

    if (tid < 4) used[tid] = 0;
    __syncthreads();

    // Scan all 8192 indices: 8 coalesced int4 loads per thread.
    const int4* idx4 = (const int4*)idx;
#pragma unroll
    for (int j = 0; j < 8; ++j) {
        const int4 v = idx4[tid + 256 * j];
        if ((v.x >> 2) == bk) used[v.x & 3] = 1;   // benign write-1 races
        if ((v.y >> 2) == bk) used[v.y & 3] = 1;
        if ((v.z >> 2) == bk) used[v.z & 3] = 1;
        if ((v.w >> 2) == bk) used[v.w & 3] = 1;
    }
    __syncthreads();

    const int w = tid >> 6;                    // wave id = which of the 4 rows
    if (!used[w]) return;                      // wave-uniform early exit

    const int t = bk * 256 + tid;              // same linear mapping as before
    const size_t off = (size_t)t << 2;         // element offset into one slice
    const float* p = x + off;

    // two accumulators to shorten the fmax dependency chain
    float4 m0 = ntload4(p);
    float4 m1 = ntload4(p + SLICE);
#pragma unroll
    for (int b = 2; b < B; b += 2) {
        float4 v0 = ntload4(p + (size_t)b * SLICE);
        float4 v1 = ntload4(p + (size_t)(b + 1) * SLICE);
        m0 = f4max(m0, v0);
        m1 = f4max(m1, v1);
    }
    *(float4*)(rowmax + off) = f4max(m0, m1);
}

// Phase 2: out[g*H + h] = max_k rowmax[idx[g*K+k]*H + h]
// rowmax is <=4 MiB and freshly written -> served from L2/L3; ~2 us.
__global__ __launch_bounds__(64) void gather_kernel(const float* __restrict__ rowmax,
                                                    const int* __restrict__ idx,
                                                    float* __restrict__ out) {
    const int g  = blockIdx.x;
    const int h4 = threadIdx.x << 2;

    float4 m = make_float4(-FLT_MAX, -FLT_MAX, -FLT_MAX, -FLT_MAX);
#pragma unroll
    for (int k = 0; k < K; ++k) {
        const int r = idx[g * K + k];                 // wave-uniform load
        float4 v = *(const float4*)(rowmax + (size_t)r * H + h4);
        m = f4max(m, v);
    }
    *(float4*)(out + (size_t)g * H + h4) = m;
}

extern "C" void kernel_launch(void* const* d_in, const int* in_sizes, int n_in,
                              void* d_out, int out_size, void* d_ws, size_t ws_size,
                              hipStream_t stream) {
    const float* x   = (const float*)d_in[0];
    const int*   idx = (const int*)d_in[1];
    float*       out = (float*)d_out;

    float* rowmax = (float*)d_ws;  // 4 MiB scratch
    rowmax_kernel<<<(A * H / 4) / 256, 256, 0, stream>>>(x, idx, rowmax);
    gather_kernel<<<G, 64, 0, stream>>>(rowmax, idx, out);
}